// Round 7
// baseline (1351.139 us; speedup 1.0000x reference)
//
#include <hip/hip_runtime.h>

#define D 128
#define NHB 64             // edge-pass blocks = hist columns (cursor runs ~16 entries = 64B)
#define MAXBUC 2048        // LDS cursor/counter capacity (N <= 131072)
#define WP 136             // LDS pitch in bf16 elems (breaks 256B-stride bank aliasing)
#define CAPB 2048          // fixed entries region per bucket (mean 1024, +32 sigma)

typedef __attribute__((ext_vector_type(8))) short bf16x8;
typedef __attribute__((ext_vector_type(4))) float f32x4;
typedef __attribute__((ext_vector_type(2))) float f32x2;   // clang-native: NT-store OK

__device__ inline ushort f2b(float f) {   // fp32 -> bf16 RNE
  unsigned u = __float_as_uint(f);
  return (ushort)((u + 0x7fffu + ((u >> 16) & 1u)) >> 16);
}

// ---- fused: [0,NHB) = bucket histogram (LDS atomics only), [NHB,..) = MFMA GEMM ----
__global__ __launch_bounds__(256) void k_gh(
    const float* __restrict__ x, const float* __restrict__ W,
    const float* __restrict__ bias, ushort* __restrict__ g, int n,
    const int* __restrict__ ei, int* __restrict__ hist, int E, int nbuc) {
  __shared__ ushort sw[128 * WP];   // 34.8 KB; hist role reuses as int[2048]

  if (blockIdx.x < NHB) {           // ---- histogram role ----
    int* h = (int*)sw;
    for (int i = threadIdx.x; i < nbuc; i += 256) h[i] = 0;
    __syncthreads();
    int per = (E + NHB - 1) / NHB;
    int e0 = blockIdx.x * per, e1 = min(E, e0 + per);
    int nv = (((E & 3) == 0) && ((e0 & 3) == 0)) ? ((e1 - e0) & ~3) : 0;
    for (int e = e0 + threadIdx.x * 4; e < e0 + nv; e += 1024) {
      int4 r4 = *(const int4*)(ei + e);
      int4 c4 = *(const int4*)(ei + E + e);
      atomicAdd(&h[r4.x >> 6], 1); atomicAdd(&h[c4.x >> 6], 1);
      atomicAdd(&h[r4.y >> 6], 1); atomicAdd(&h[c4.y >> 6], 1);
      atomicAdd(&h[r4.z >> 6], 1); atomicAdd(&h[c4.z >> 6], 1);
      atomicAdd(&h[r4.w >> 6], 1); atomicAdd(&h[c4.w >> 6], 1);
    }
    for (int e = e0 + nv + threadIdx.x; e < e1; e += 256) {
      atomicAdd(&h[ei[e] >> 6], 1);
      atomicAdd(&h[ei[E + e] >> 6], 1);
    }
    __syncthreads();
    for (int i = threadIdx.x; i < nbuc; i += 256)
      hist[(size_t)i * NHB + blockIdx.x] = h[i];
    return;                          // block-uniform branch
  }

  // ---- GEMM role: g(bf16) = x @ W^T + b (round-0 proven body) ----
  const int tid = threadIdx.x;
  const int row0 = (blockIdx.x - NHB) * 64;

  for (int i = tid; i < 128 * 32; i += 256) {   // stage W fp32->bf16
    int o = i >> 5, kg = i & 31;
    float4 v = ((const float4*)W)[i];
    ushort4 h;
    h.x = f2b(v.x); h.y = f2b(v.y); h.z = f2b(v.z); h.w = f2b(v.w);
    *(ushort4*)(&sw[o * WP + kg * 4]) = h;
  }
  __syncthreads();

  const int wid = tid >> 6, lane = tid & 63;
  const int wr0 = wid * 16;
  const int col = lane & 15, quad = lane >> 4;
  int arow = row0 + wr0 + col;
  if (arow >= n) arow = n - 1;           // clamp loads; stores guarded
  const float4* xrow = (const float4*)(x + (size_t)arow * D);

  f32x4 acc[8] = {};
#pragma unroll
  for (int s = 0; s < 4; ++s) {          // K = 4 x 32
    float4 v0 = xrow[s * 8 + quad * 2];
    float4 v1 = xrow[s * 8 + quad * 2 + 1];
    bf16x8 a;
    a[0] = f2b(v0.x); a[1] = f2b(v0.y); a[2] = f2b(v0.z); a[3] = f2b(v0.w);
    a[4] = f2b(v1.x); a[5] = f2b(v1.y); a[6] = f2b(v1.z); a[7] = f2b(v1.w);
#pragma unroll
    for (int t = 0; t < 8; ++t) {
      bf16x8 bfr = *(const bf16x8*)(&sw[(t * 16 + col) * WP + s * 32 + quad * 8]);
      acc[t] = __builtin_amdgcn_mfma_f32_16x16x32_bf16(a, bfr, acc[t], 0, 0, 0);
    }
  }

  __syncthreads();   // reuse sw for output bounce
#pragma unroll
  for (int t = 0; t < 8; ++t) {
    float bcol = bias[t * 16 + col];
#pragma unroll
    for (int r = 0; r < 4; ++r) {
      int row = wr0 + quad * 4 + r;      // C layout: col=lane&15, row=quad*4+reg
      sw[row * WP + t * 16 + col] = f2b(acc[t][r] + bcol);
    }
  }
  __syncthreads();
  for (int i = tid; i < 64 * 16; i += 256) {
    int r = i >> 4, c = i & 15;
    int gr = row0 + r;
    if (gr < n)
      *(uint4*)(&g[(size_t)gr * D + c * 8]) = *(const uint4*)(&sw[r * WP + c * 8]);
  }
}

// ---- scatter: cursor starts derived from hist locally (no alloc kernel, no global ctr) ----
#define PROC(rr, cc)                                        \
  {                                                         \
    int bb = (cc) >> 6;                                     \
    int p = atomicAdd(&cur[bb], 1);                         \
    if (p < (bb + 1) * CAPB) entries[p] = ((rr) << 6) | ((cc) & 63); \
    bb = (rr) >> 6;                                         \
    p = atomicAdd(&cur[bb], 1);                             \
    if (p < (bb + 1) * CAPB) entries[p] = ((cc) << 6) | ((rr) & 63); \
  }

__global__ __launch_bounds__(256) void k_scatter(const int* __restrict__ ei,
                                                 const int* __restrict__ hist,
                                                 int* __restrict__ bend,
                                                 int* __restrict__ entries,
                                                 int E, int nbuc) {
  __shared__ int cur[MAXBUC];
  const int jb = blockIdx.x;
  for (int b = threadIdx.x; b < nbuc; b += 256) {   // column-prefix of hist row up to jb
    const int4* r4p = (const int4*)(hist + (size_t)b * NHB);
    int s = 0;
    int full = jb >> 2;
    for (int q = 0; q < full; ++q) { int4 v = r4p[q]; s += v.x + v.y + v.z + v.w; }
    int rem = jb & 3;
    if (rem) { int4 v = r4p[full]; s += v.x; if (rem > 1) s += v.y; if (rem > 2) s += v.z; }
    cur[b] = b * CAPB + s;
    if (jb == NHB - 1)
      bend[b] = b * CAPB + s + hist[(size_t)b * NHB + (NHB - 1)];
  }
  __syncthreads();
  int per = (E + NHB - 1) / NHB;
  int e0 = jb * per, e1 = min(E, e0 + per);
  int nv = (((E & 3) == 0) && ((e0 & 3) == 0)) ? ((e1 - e0) & ~3) : 0;
  for (int e = e0 + threadIdx.x * 4; e < e0 + nv; e += 1024) {
    int4 r4 = *(const int4*)(ei + e);
    int4 c4 = *(const int4*)(ei + E + e);
    PROC(r4.x, c4.x); PROC(r4.y, c4.y); PROC(r4.z, c4.z); PROC(r4.w, c4.w);
  }
  for (int e = e0 + nv + threadIdx.x; e < e1; e += 256) {
    int r = ei[e], c = ei[E + e];
    PROC(r, c);
  }
}

// ---- dis = rsqrt(deg+1) from per-bucket entries (contiguous reads, LDS bins) ----
__global__ __launch_bounds__(256) void k_dis(const int* __restrict__ entries,
                                             const int* __restrict__ bend,
                                             float* __restrict__ dis, int N) {
  __shared__ int bin[64];
  const int b = blockIdx.x;
  if (threadIdx.x < 64) bin[threadIdx.x] = 0;
  __syncthreads();
  int s0 = b * CAPB;
  int e1 = min(bend[b], s0 + CAPB);
  for (int i = s0 + threadIdx.x; i < e1; i += 256)
    atomicAdd(&bin[entries[i] & 63], 1);
  __syncthreads();
  int gn = b * 64 + threadIdx.x;
  if (threadIdx.x < 64 && gn < N)
    dis[gn] = rsqrtf((float)(bin[threadIdx.x] + 1));
}

// ---- aggregation v2: src-sorted sweep + edge-parallel LDS accumulation ----
// Sort bucket entries by src>>9 (256-bin counting sort) so ALL blocks sweep g
// in ascending-src order concurrently -> fetched g rows get reused via L2/L3
// before eviction. Accumulate into LDS (ds_add_f32); dest-grouping no longer
// needed. accLo/accHi split so lane l hits bank l%32 (2-way = free, m136).
#define ACC8(EN, DU)                                                      \
  {                                                                       \
    uint a_ = g32[(size_t)((EN) >> 6) * 64 + lane];                       \
    atomicAdd(&accLo[((EN) & 63) * 64 + lane],                            \
              (DU) * __uint_as_float(a_ << 16));                          \
    atomicAdd(&accHi[((EN) & 63) * 64 + lane],                            \
              (DU) * __uint_as_float(a_ & 0xffff0000u));                  \
  }

__global__ __launch_bounds__(512) void k_aggsort(const int* __restrict__ entries,
                                                 const int* __restrict__ bend,
                                                 const uint* __restrict__ g32,
                                                 const float* __restrict__ dis,
                                                 float* __restrict__ out, int N) {
  __shared__ float accLo[64 * 64];   // 16 KB  [dest][lane] = col 2*lane
  __shared__ float accHi[64 * 64];   // 16 KB  [dest][lane] = col 2*lane+1
  __shared__ int slds[CAPB];         // 8 KB   src-sorted entries
  __shared__ int bin[256], sc[256];  // 2 KB   src-high bins
  const int b = blockIdx.x;
  const int s0 = b * CAPB;
  const int tot = min(bend[b] - s0, CAPB);
  const int e0 = s0 + tot;
  const int lane = threadIdx.x & 63;
  const int wid = threadIdx.x >> 6;

  for (int i = threadIdx.x; i < 64 * 64; i += 512) { accLo[i] = 0.f; accHi[i] = 0.f; }
  if (threadIdx.x < 256) bin[threadIdx.x] = 0;
  __syncthreads();

  // count src-high (src>>9 = en>>15; <= 195 bins for N=100k)
  for (int i = s0 + threadIdx.x; i < e0; i += 512)
    atomicAdd(&bin[(entries[i] >> 15) & 255], 1);
  __syncthreads();

  // exclusive scan over 256 bins (Hillis-Steele, uniform barriers)
  int v = (threadIdx.x < 256) ? bin[threadIdx.x] : 0;
  if (threadIdx.x < 256) sc[threadIdx.x] = v;
  __syncthreads();
  for (int o = 1; o < 256; o <<= 1) {
    int t = (threadIdx.x < 256 && threadIdx.x >= (unsigned)o) ? sc[threadIdx.x - o] : 0;
    __syncthreads();
    if (threadIdx.x < 256) sc[threadIdx.x] += t;
    __syncthreads();
  }
  if (threadIdx.x < 256) bin[threadIdx.x] = sc[threadIdx.x] - v;   // cursor
  __syncthreads();

  // scatter entries into slds ordered by src-high (last global read of entries)
  for (int i = s0 + threadIdx.x; i < e0; i += 512) {
    int en = __builtin_nontemporal_load(entries + i);
    int p = atomicAdd(&bin[(en >> 15) & 255], 1);
    slds[p] = en;
  }
  __syncthreads();

  // sweep slds in ascending-src order; 8 waves interleave 64-entry groups
  for (int base = wid * 64; base < tot; base += 512) {
    int cnt = tot - base; if (cnt > 64) cnt = 64;
    int idx = base + lane;
    int my = (idx < tot) ? slds[idx] : 0;
    float dl = (idx < tot) ? dis[my >> 6] : 0.f;
    int k = 0;
    for (; k + 7 < cnt; k += 8) {
      int e0_ = __shfl(my, k);     int e1_ = __shfl(my, k + 1);
      int e2_ = __shfl(my, k + 2); int e3_ = __shfl(my, k + 3);
      int e4_ = __shfl(my, k + 4); int e5_ = __shfl(my, k + 5);
      int e6_ = __shfl(my, k + 6); int e7_ = __shfl(my, k + 7);
      float d0 = __shfl(dl, k);     float d1 = __shfl(dl, k + 1);
      float d2 = __shfl(dl, k + 2); float d3 = __shfl(dl, k + 3);
      float d4 = __shfl(dl, k + 4); float d5 = __shfl(dl, k + 5);
      float d6 = __shfl(dl, k + 6); float d7 = __shfl(dl, k + 7);
      ACC8(e0_, d0); ACC8(e1_, d1); ACC8(e2_, d2); ACC8(e3_, d3);
      ACC8(e4_, d4); ACC8(e5_, d5); ACC8(e6_, d6); ACC8(e7_, d7);
    }
    for (; k < cnt; ++k) {
      int en = __shfl(my, k);
      float du = __shfl(dl, k);
      ACC8(en, du);
    }
  }
  __syncthreads();

  // epilogue: self-loop + relu + NT store; 8 waves x 8 dests
  for (int j = 0; j < 8; ++j) {
    int ln = wid * 8 + j;
    int gn = b * 64 + ln;
    if (gn >= N) break;
    float dv = dis[gn];
    uint us = g32[(size_t)gn * 64 + lane];
    float lo = (accLo[ln * 64 + lane] + __uint_as_float(us << 16) * dv) * dv;
    float hi = (accHi[ln * 64 + lane] + __uint_as_float(us & 0xffff0000u) * dv) * dv;
    f32x2 o;
    o.x = fmaxf(lo, 0.f);
    o.y = fmaxf(hi, 0.f);
    __builtin_nontemporal_store(o, (f32x2*)out + (size_t)gn * 64 + lane);
  }
}

extern "C" void kernel_launch(void* const* d_in, const int* in_sizes, int n_in,
                              void* d_out, int out_size, void* d_ws, size_t ws_size,
                              hipStream_t stream) {
  const float* x  = (const float*)d_in[0];
  const int*   ei = (const int*)d_in[1];
  const float* W  = (const float*)d_in[2];
  const float* b  = (const float*)d_in[3];
  float* out = (float*)d_out;

  const int N = in_sizes[0] / D;
  const int E = in_sizes[1] / 2;
  const int NBUC = (N + 63) / 64;            // 1563 for N=100k (<= MAXBUC)

  char* ws = (char*)d_ws;
  size_t off = 0;
  ushort* g    = (ushort*)(ws + off); off += (size_t)N * D * 2;          // 25.6 MB
  off = (off + 255) & ~(size_t)255;
  float* dis   = (float*)(ws + off);  off += (size_t)N * 4;
  off = (off + 255) & ~(size_t)255;
  int* bend    = (int*)(ws + off);    off += (size_t)NBUC * 4;
  off = (off + 255) & ~(size_t)255;
  int* hist    = (int*)(ws + off);    off += (size_t)NBUC * NHB * 4;     // 400 KB
  off = (off + 255) & ~(size_t)255;
  int* entries = (int*)(ws + off);    off += (size_t)NBUC * CAPB * 4;    // 12.8 MB

  k_gh<<<NHB + NBUC, 256, 0, stream>>>(x, W, b, g, N, ei, hist, E, NBUC);
  k_scatter<<<NHB, 256, 0, stream>>>(ei, hist, bend, entries, E, NBUC);
  k_dis<<<NBUC, 256, 0, stream>>>(entries, bend, dis, N);
  k_aggsort<<<NBUC, 512, 0, stream>>>(entries, bend, (const uint*)g, dis, out, N);
}

// Round 8
// 223.489 us; speedup vs baseline: 6.0457x; 6.0457x over previous
//
#include <hip/hip_runtime.h>

#define D 128
#define NHB 128            // edge chunks = hist columns; 128 blocks for scatter
#define STH 512            // scatter threads per block (8 waves)
#define MAXBUC 2048        // LDS cursor/counter capacity (N <= 131072)
#define WP 136             // LDS pitch in bf16 elems (breaks 256B-stride bank aliasing)
#define CAPB 2048          // fixed entries region per bucket (mean 1024, +32 sigma)

typedef __attribute__((ext_vector_type(8))) short bf16x8;
typedef __attribute__((ext_vector_type(4))) float f32x4;
typedef __attribute__((ext_vector_type(2))) float f32x2;   // clang-native: NT-store OK

__device__ inline ushort f2b(float f) {   // fp32 -> bf16 RNE
  unsigned u = __float_as_uint(f);
  return (ushort)((u + 0x7fffu + ((u >> 16) & 1u)) >> 16);
}

__device__ inline int chunk_per(int E) {   // chunk length, multiple of 4 (int4-aligned)
  return (((E + NHB - 1) / NHB) + 3) & ~3;
}

// ---- fused: [0,NHB) = bucket histogram (LDS atomics only), [NHB,..) = MFMA GEMM ----
__global__ __launch_bounds__(256) void k_gh(
    const float* __restrict__ x, const float* __restrict__ W,
    const float* __restrict__ bias, ushort* __restrict__ g, int n,
    const int* __restrict__ ei, int* __restrict__ hist, int E, int nbuc) {
  __shared__ ushort sw[128 * WP];   // 34.8 KB; hist role reuses as int[2048]

  if (blockIdx.x < NHB) {           // ---- histogram role ----
    int* h = (int*)sw;
    for (int i = threadIdx.x; i < nbuc; i += 256) h[i] = 0;
    __syncthreads();
    int per = chunk_per(E);
    int e0 = blockIdx.x * per, e1 = min(E, e0 + per);
    if (e0 < e1) {
      int nv = (e1 - e0) & ~3;      // e0 % 4 == 0 by construction
      for (int e = e0 + threadIdx.x * 4; e < e0 + nv; e += 1024) {
        int4 r4 = *(const int4*)(ei + e);
        int4 c4 = *(const int4*)(ei + E + e);
        atomicAdd(&h[r4.x >> 6], 1); atomicAdd(&h[c4.x >> 6], 1);
        atomicAdd(&h[r4.y >> 6], 1); atomicAdd(&h[c4.y >> 6], 1);
        atomicAdd(&h[r4.z >> 6], 1); atomicAdd(&h[c4.z >> 6], 1);
        atomicAdd(&h[r4.w >> 6], 1); atomicAdd(&h[c4.w >> 6], 1);
      }
      for (int e = e0 + nv + threadIdx.x; e < e1; e += 256) {
        atomicAdd(&h[ei[e] >> 6], 1);
        atomicAdd(&h[ei[E + e] >> 6], 1);
      }
    }
    __syncthreads();
    for (int i = threadIdx.x; i < nbuc; i += 256)
      hist[(size_t)i * NHB + blockIdx.x] = h[i];
    return;                          // block-uniform branch
  }

  // ---- GEMM role: g(bf16) = x @ W^T + b (round-0 proven body) ----
  const int tid = threadIdx.x;
  const int row0 = (blockIdx.x - NHB) * 64;

  for (int i = tid; i < 128 * 32; i += 256) {   // stage W fp32->bf16
    int o = i >> 5, kg = i & 31;
    float4 v = ((const float4*)W)[i];
    ushort4 h;
    h.x = f2b(v.x); h.y = f2b(v.y); h.z = f2b(v.z); h.w = f2b(v.w);
    *(ushort4*)(&sw[o * WP + kg * 4]) = h;
  }
  __syncthreads();

  const int wid = tid >> 6, lane = tid & 63;
  const int wr0 = wid * 16;
  const int col = lane & 15, quad = lane >> 4;
  int arow = row0 + wr0 + col;
  if (arow >= n) arow = n - 1;           // clamp loads; stores guarded
  const float4* xrow = (const float4*)(x + (size_t)arow * D);

  f32x4 acc[8] = {};
#pragma unroll
  for (int s = 0; s < 4; ++s) {          // K = 4 x 32
    float4 v0 = xrow[s * 8 + quad * 2];
    float4 v1 = xrow[s * 8 + quad * 2 + 1];
    bf16x8 a;
    a[0] = f2b(v0.x); a[1] = f2b(v0.y); a[2] = f2b(v0.z); a[3] = f2b(v0.w);
    a[4] = f2b(v1.x); a[5] = f2b(v1.y); a[6] = f2b(v1.z); a[7] = f2b(v1.w);
#pragma unroll
    for (int t = 0; t < 8; ++t) {
      bf16x8 bfr = *(const bf16x8*)(&sw[(t * 16 + col) * WP + s * 32 + quad * 8]);
      acc[t] = __builtin_amdgcn_mfma_f32_16x16x32_bf16(a, bfr, acc[t], 0, 0, 0);
    }
  }

  __syncthreads();   // reuse sw for output bounce
#pragma unroll
  for (int t = 0; t < 8; ++t) {
    float bcol = bias[t * 16 + col];
#pragma unroll
    for (int r = 0; r < 4; ++r) {
      int row = wr0 + quad * 4 + r;      // C layout: col=lane&15, row=quad*4+reg
      sw[row * WP + t * 16 + col] = f2b(acc[t][r] + bcol);
    }
  }
  __syncthreads();
  for (int i = tid; i < 64 * 16; i += 256) {
    int r = i >> 4, c = i & 15;
    int gr = row0 + r;
    if (gr < n)
      *(uint4*)(&g[(size_t)gr * D + c * 8]) = *(const uint4*)(&sw[r * WP + c * 8]);
  }
}

// ---- scatter: 128 blocks x 512 threads; cursor starts derived from hist locally ----
#define PROC(rr, cc)                                        \
  {                                                         \
    int bb = (cc) >> 6;                                     \
    int p = atomicAdd(&cur[bb], 1);                         \
    if (p < (bb + 1) * CAPB) entries[p] = ((rr) << 6) | ((cc) & 63); \
    bb = (rr) >> 6;                                         \
    p = atomicAdd(&cur[bb], 1);                             \
    if (p < (bb + 1) * CAPB) entries[p] = ((cc) << 6) | ((rr) & 63); \
  }

__global__ __launch_bounds__(STH) void k_scatter(const int* __restrict__ ei,
                                                 const int* __restrict__ hist,
                                                 int* __restrict__ bend,
                                                 int* __restrict__ entries,
                                                 int E, int nbuc) {
  __shared__ int cur[MAXBUC];
  const int jb = blockIdx.x;
  for (int b = threadIdx.x; b < nbuc; b += STH) {   // column-prefix of hist row up to jb
    const int4* r4p = (const int4*)(hist + (size_t)b * NHB);
    int s = 0;
    int full = jb >> 2;
    for (int q = 0; q < full; ++q) { int4 v = r4p[q]; s += v.x + v.y + v.z + v.w; }
    int rem = jb & 3;
    if (rem) { int4 v = r4p[full]; s += v.x; if (rem > 1) s += v.y; if (rem > 2) s += v.z; }
    cur[b] = b * CAPB + s;
    if (jb == NHB - 1)
      bend[b] = b * CAPB + s + hist[(size_t)b * NHB + (NHB - 1)];
  }
  __syncthreads();
  int per = chunk_per(E);
  int e0 = jb * per, e1 = min(E, e0 + per);
  if (e0 < e1) {
    int nv = (e1 - e0) & ~3;      // e0 % 4 == 0 by construction
    for (int e = e0 + threadIdx.x * 4; e < e0 + nv; e += STH * 4) {
      int4 r4 = *(const int4*)(ei + e);
      int4 c4 = *(const int4*)(ei + E + e);
      PROC(r4.x, c4.x); PROC(r4.y, c4.y); PROC(r4.z, c4.z); PROC(r4.w, c4.w);
    }
    for (int e = e0 + nv + threadIdx.x; e < e1; e += STH) {
      int r = ei[e], c = ei[E + e];
      PROC(r, c);
    }
  }
}

// ---- dis = rsqrt(deg+1) from per-bucket entries (contiguous reads, LDS bins) ----
__global__ __launch_bounds__(256) void k_dis(const int* __restrict__ entries,
                                             const int* __restrict__ bend,
                                             float* __restrict__ dis, int N) {
  __shared__ int bin[64];
  const int b = blockIdx.x;
  if (threadIdx.x < 64) bin[threadIdx.x] = 0;
  __syncthreads();
  int s0 = b * CAPB;
  int e1 = min(bend[b], s0 + CAPB);
  for (int i = s0 + threadIdx.x; i < e1; i += 256)
    atomicAdd(&bin[entries[i] & 63], 1);
  __syncthreads();
  int gn = b * 64 + threadIdx.x;
  if (threadIdx.x < 64 && gn < N)
    dis[gn] = rsqrtf((float)(bin[threadIdx.x] + 1));
}

// ---- fused counting-sort (LDS) + pull aggregation; 8 waves x 8 nodes (round-6 proven) ----
__global__ __launch_bounds__(512) void k_aggsort(const int* __restrict__ entries,
                                                 const int* __restrict__ bend,
                                                 const uint* __restrict__ g32,
                                                 const float* __restrict__ dis,
                                                 float* __restrict__ out, int N) {
  __shared__ int slds[CAPB];
  __shared__ int bin[64], sc[64], nst[64], ncn[64];
  const int b = blockIdx.x;
  const int s0 = b * CAPB;
  int tot = min(bend[b] - s0, CAPB);
  const int e0 = s0 + tot;

  // count
  if (threadIdx.x < 64) bin[threadIdx.x] = 0;
  __syncthreads();
  for (int i = s0 + threadIdx.x; i < e0; i += 512)
    atomicAdd(&bin[entries[i] & 63], 1);
  __syncthreads();

  // exclusive scan over 64 bins
  int v = (threadIdx.x < 64) ? bin[threadIdx.x] : 0;
  if (threadIdx.x < 64) sc[threadIdx.x] = v;
  __syncthreads();
  for (int o = 1; o < 64; o <<= 1) {
    int t = (threadIdx.x < 64 && threadIdx.x >= (unsigned)o) ? sc[threadIdx.x - o] : 0;
    __syncthreads();
    if (threadIdx.x < 64) sc[threadIdx.x] += t;
    __syncthreads();
  }
  if (threadIdx.x < 64) {
    int start = sc[threadIdx.x] - v;   // 0-based within bucket
    nst[threadIdx.x] = start;
    ncn[threadIdx.x] = v;
    bin[threadIdx.x] = start;          // becomes cursor
  }
  __syncthreads();

  // scatter sorted-by-dest srcs into LDS (last use of entries -> NT load)
  for (int i = s0 + threadIdx.x; i < e0; i += 512) {
    int en = __builtin_nontemporal_load(entries + i);
    int p = atomicAdd(&bin[en & 63], 1);
    slds[p] = en >> 6;
  }
  __syncthreads();

  // gather: 8 waves x 8 nodes each, proven ILP-8 body
  const int wid = threadIdx.x >> 6, lane = threadIdx.x & 63;
  for (int j = 0; j < 8; ++j) {
    int ln = wid * 8 + j;
    int gn = b * 64 + ln;
    if (gn >= N) break;                // only trips in the final partial bucket
    int st = nst[ln], cn = ncn[ln];
    float dv = dis[gn];
    uint us = g32[(size_t)gn * 64 + lane];
    float ax = __uint_as_float(us << 16) * dv;          // self: dis_v * g_v
    float ay = __uint_as_float(us & 0xffff0000u) * dv;

    for (int base = 0; base < cn; base += 64) {
      int cnt = cn - base; if (cnt > 64) cnt = 64;
      int idx = base + lane;
      int my = (idx < cn) ? slds[st + idx] : 0;
      float dl = (idx < cn) ? dis[my] : 0.f;
      int k = 0;
      for (; k + 7 < cnt; k += 8) {
        int u0 = __shfl(my, k);     int u1 = __shfl(my, k + 1);
        int u2 = __shfl(my, k + 2); int u3 = __shfl(my, k + 3);
        int u4 = __shfl(my, k + 4); int u5 = __shfl(my, k + 5);
        int u6 = __shfl(my, k + 6); int u7 = __shfl(my, k + 7);
        float d0 = __shfl(dl, k);     float d1 = __shfl(dl, k + 1);
        float d2 = __shfl(dl, k + 2); float d3 = __shfl(dl, k + 3);
        float d4 = __shfl(dl, k + 4); float d5 = __shfl(dl, k + 5);
        float d6 = __shfl(dl, k + 6); float d7 = __shfl(dl, k + 7);
        uint a0 = g32[(size_t)u0 * 64 + lane];
        uint a1 = g32[(size_t)u1 * 64 + lane];
        uint a2 = g32[(size_t)u2 * 64 + lane];
        uint a3 = g32[(size_t)u3 * 64 + lane];
        uint a4 = g32[(size_t)u4 * 64 + lane];
        uint a5 = g32[(size_t)u5 * 64 + lane];
        uint a6 = g32[(size_t)u6 * 64 + lane];
        uint a7 = g32[(size_t)u7 * 64 + lane];
        ax = fmaf(d0, __uint_as_float(a0 << 16), ax);
        ay = fmaf(d0, __uint_as_float(a0 & 0xffff0000u), ay);
        ax = fmaf(d1, __uint_as_float(a1 << 16), ax);
        ay = fmaf(d1, __uint_as_float(a1 & 0xffff0000u), ay);
        ax = fmaf(d2, __uint_as_float(a2 << 16), ax);
        ay = fmaf(d2, __uint_as_float(a2 & 0xffff0000u), ay);
        ax = fmaf(d3, __uint_as_float(a3 << 16), ax);
        ay = fmaf(d3, __uint_as_float(a3 & 0xffff0000u), ay);
        ax = fmaf(d4, __uint_as_float(a4 << 16), ax);
        ay = fmaf(d4, __uint_as_float(a4 & 0xffff0000u), ay);
        ax = fmaf(d5, __uint_as_float(a5 << 16), ax);
        ay = fmaf(d5, __uint_as_float(a5 & 0xffff0000u), ay);
        ax = fmaf(d6, __uint_as_float(a6 << 16), ax);
        ay = fmaf(d6, __uint_as_float(a6 & 0xffff0000u), ay);
        ax = fmaf(d7, __uint_as_float(a7 << 16), ax);
        ay = fmaf(d7, __uint_as_float(a7 & 0xffff0000u), ay);
      }
      for (; k < cnt; ++k) {
        int u = __shfl(my, k);
        float du = __shfl(dl, k);
        uint a = g32[(size_t)u * 64 + lane];
        ax = fmaf(du, __uint_as_float(a << 16), ax);
        ay = fmaf(du, __uint_as_float(a & 0xffff0000u), ay);
      }
    }
    f32x2 o;
    o.x = fmaxf(ax * dv, 0.f);
    o.y = fmaxf(ay * dv, 0.f);
    __builtin_nontemporal_store(o, (f32x2*)out + (size_t)gn * 64 + lane);
  }
}

extern "C" void kernel_launch(void* const* d_in, const int* in_sizes, int n_in,
                              void* d_out, int out_size, void* d_ws, size_t ws_size,
                              hipStream_t stream) {
  const float* x  = (const float*)d_in[0];
  const int*   ei = (const int*)d_in[1];
  const float* W  = (const float*)d_in[2];
  const float* b  = (const float*)d_in[3];
  float* out = (float*)d_out;

  const int N = in_sizes[0] / D;
  const int E = in_sizes[1] / 2;
  const int NBUC = (N + 63) / 64;            // 1563 for N=100k (<= MAXBUC)

  char* ws = (char*)d_ws;
  size_t off = 0;
  ushort* g    = (ushort*)(ws + off); off += (size_t)N * D * 2;          // 25.6 MB
  off = (off + 255) & ~(size_t)255;
  float* dis   = (float*)(ws + off);  off += (size_t)N * 4;
  off = (off + 255) & ~(size_t)255;
  int* bend    = (int*)(ws + off);    off += (size_t)NBUC * 4;
  off = (off + 255) & ~(size_t)255;
  int* hist    = (int*)(ws + off);    off += (size_t)NBUC * NHB * 4;     // 800 KB
  off = (off + 255) & ~(size_t)255;
  int* entries = (int*)(ws + off);    off += (size_t)NBUC * CAPB * 4;    // 12.8 MB

  k_gh<<<NHB + NBUC, 256, 0, stream>>>(x, W, b, g, N, ei, hist, E, NBUC);
  k_scatter<<<NHB, STH, 0, stream>>>(ei, hist, bend, entries, E, NBUC);
  k_dis<<<NBUC, 256, 0, stream>>>(entries, bend, dis, N);
  k_aggsort<<<NBUC, 512, 0, stream>>>(entries, bend, (const uint*)g, dis, out, N);
}

// Round 9
// 221.015 us; speedup vs baseline: 6.1134x; 1.0112x over previous
//
#include <hip/hip_runtime.h>

#define D 128
#define NHB 128            // edge chunks = hist columns; 128 blocks for scatter
#define STH 512            // scatter threads per block (8 waves)
#define MAXBUC 2048        // LDS cursor/counter capacity (N <= 131072)
#define WP 136             // LDS pitch in bf16 elems (breaks 256B-stride bank aliasing)
#define CAPB 2048          // fixed entries region per bucket (mean 1024, +32 sigma)

typedef __attribute__((ext_vector_type(8))) short bf16x8;
typedef __attribute__((ext_vector_type(4))) float f32x4;
typedef __attribute__((ext_vector_type(2))) float f32x2;   // clang-native: NT-store OK

__device__ inline ushort f2b(float f) {   // fp32 -> bf16 RNE
  unsigned u = __float_as_uint(f);
  return (ushort)((u + 0x7fffu + ((u >> 16) & 1u)) >> 16);
}

__device__ inline int chunk_per(int E) {   // chunk length, multiple of 4 (int4-aligned)
  return (((E + NHB - 1) / NHB) + 3) & ~3;
}

// ---- fused: [0,NHB) = bucket histogram (LDS atomics only), [NHB,..) = MFMA GEMM ----
__global__ __launch_bounds__(256) void k_gh(
    const float* __restrict__ x, const float* __restrict__ W,
    const float* __restrict__ bias, ushort* __restrict__ g, int n,
    const int* __restrict__ ei, int* __restrict__ hist, int E, int nbuc) {
  __shared__ ushort sw[128 * WP];   // 34.8 KB; hist role reuses as int[2048]

  if (blockIdx.x < NHB) {           // ---- histogram role ----
    int* h = (int*)sw;
    for (int i = threadIdx.x; i < nbuc; i += 256) h[i] = 0;
    __syncthreads();
    int per = chunk_per(E);
    int e0 = blockIdx.x * per, e1 = min(E, e0 + per);
    if (e0 < e1) {
      int nv = (e1 - e0) & ~3;      // e0 % 4 == 0 by construction
      for (int e = e0 + threadIdx.x * 4; e < e0 + nv; e += 1024) {
        int4 r4 = *(const int4*)(ei + e);
        int4 c4 = *(const int4*)(ei + E + e);
        atomicAdd(&h[r4.x >> 6], 1); atomicAdd(&h[c4.x >> 6], 1);
        atomicAdd(&h[r4.y >> 6], 1); atomicAdd(&h[c4.y >> 6], 1);
        atomicAdd(&h[r4.z >> 6], 1); atomicAdd(&h[c4.z >> 6], 1);
        atomicAdd(&h[r4.w >> 6], 1); atomicAdd(&h[c4.w >> 6], 1);
      }
      for (int e = e0 + nv + threadIdx.x; e < e1; e += 256) {
        atomicAdd(&h[ei[e] >> 6], 1);
        atomicAdd(&h[ei[E + e] >> 6], 1);
      }
    }
    __syncthreads();
    for (int i = threadIdx.x; i < nbuc; i += 256)
      hist[(size_t)i * NHB + blockIdx.x] = h[i];
    return;                          // block-uniform branch
  }

  // ---- GEMM role: g(bf16) = x @ W^T + b (round-0 proven body) ----
  const int tid = threadIdx.x;
  const int row0 = (blockIdx.x - NHB) * 64;

  for (int i = tid; i < 128 * 32; i += 256) {   // stage W fp32->bf16
    int o = i >> 5, kg = i & 31;
    float4 v = ((const float4*)W)[i];
    ushort4 h;
    h.x = f2b(v.x); h.y = f2b(v.y); h.z = f2b(v.z); h.w = f2b(v.w);
    *(ushort4*)(&sw[o * WP + kg * 4]) = h;
  }
  __syncthreads();

  const int wid = tid >> 6, lane = tid & 63;
  const int wr0 = wid * 16;
  const int col = lane & 15, quad = lane >> 4;
  int arow = row0 + wr0 + col;
  if (arow >= n) arow = n - 1;           // clamp loads; stores guarded
  const float4* xrow = (const float4*)(x + (size_t)arow * D);

  f32x4 acc[8] = {};
#pragma unroll
  for (int s = 0; s < 4; ++s) {          // K = 4 x 32
    float4 v0 = xrow[s * 8 + quad * 2];
    float4 v1 = xrow[s * 8 + quad * 2 + 1];
    bf16x8 a;
    a[0] = f2b(v0.x); a[1] = f2b(v0.y); a[2] = f2b(v0.z); a[3] = f2b(v0.w);
    a[4] = f2b(v1.x); a[5] = f2b(v1.y); a[6] = f2b(v1.z); a[7] = f2b(v1.w);
#pragma unroll
    for (int t = 0; t < 8; ++t) {
      bf16x8 bfr = *(const bf16x8*)(&sw[(t * 16 + col) * WP + s * 32 + quad * 8]);
      acc[t] = __builtin_amdgcn_mfma_f32_16x16x32_bf16(a, bfr, acc[t], 0, 0, 0);
    }
  }

  __syncthreads();   // reuse sw for output bounce
#pragma unroll
  for (int t = 0; t < 8; ++t) {
    float bcol = bias[t * 16 + col];
#pragma unroll
    for (int r = 0; r < 4; ++r) {
      int row = wr0 + quad * 4 + r;      // C layout: col=lane&15, row=quad*4+reg
      sw[row * WP + t * 16 + col] = f2b(acc[t][r] + bcol);
    }
  }
  __syncthreads();
  for (int i = tid; i < 64 * 16; i += 256) {
    int r = i >> 4, c = i & 15;
    int gr = row0 + r;
    if (gr < n)
      *(uint4*)(&g[(size_t)gr * D + c * 8]) = *(const uint4*)(&sw[r * WP + c * 8]);
  }
}

// ---- scatter: 128 blocks x 512 threads; cursor starts derived from hist locally ----
#define PROC(rr, cc)                                        \
  {                                                         \
    int bb = (cc) >> 6;                                     \
    int p = atomicAdd(&cur[bb], 1);                         \
    if (p < (bb + 1) * CAPB) entries[p] = ((rr) << 6) | ((cc) & 63); \
    bb = (rr) >> 6;                                         \
    p = atomicAdd(&cur[bb], 1);                             \
    if (p < (bb + 1) * CAPB) entries[p] = ((cc) << 6) | ((rr) & 63); \
  }

__global__ __launch_bounds__(STH) void k_scatter(const int* __restrict__ ei,
                                                 const int* __restrict__ hist,
                                                 int* __restrict__ bend,
                                                 int* __restrict__ entries,
                                                 int E, int nbuc) {
  __shared__ int cur[MAXBUC];
  const int jb = blockIdx.x;
  for (int b = threadIdx.x; b < nbuc; b += STH) {   // column-prefix of hist row up to jb
    const int4* r4p = (const int4*)(hist + (size_t)b * NHB);
    int s = 0;
    int full = jb >> 2;
    for (int q = 0; q < full; ++q) { int4 v = r4p[q]; s += v.x + v.y + v.z + v.w; }
    int rem = jb & 3;
    if (rem) { int4 v = r4p[full]; s += v.x; if (rem > 1) s += v.y; if (rem > 2) s += v.z; }
    cur[b] = b * CAPB + s;
    if (jb == NHB - 1)
      bend[b] = b * CAPB + s + hist[(size_t)b * NHB + (NHB - 1)];
  }
  __syncthreads();
  int per = chunk_per(E);
  int e0 = jb * per, e1 = min(E, e0 + per);
  if (e0 < e1) {
    int nv = (e1 - e0) & ~3;      // e0 % 4 == 0 by construction
    for (int e = e0 + threadIdx.x * 4; e < e0 + nv; e += STH * 4) {
      int4 r4 = *(const int4*)(ei + e);
      int4 c4 = *(const int4*)(ei + E + e);
      PROC(r4.x, c4.x); PROC(r4.y, c4.y); PROC(r4.z, c4.z); PROC(r4.w, c4.w);
    }
    for (int e = e0 + nv + threadIdx.x; e < e1; e += STH) {
      int r = ei[e], c = ei[E + e];
      PROC(r, c);
    }
  }
}

// ---- disn: per-node degree -> dis + nodese(bucket-local start, count) ----
// Count+scan moved here from aggsort (it duplicated this work and re-read entries).
__global__ __launch_bounds__(256) void k_disn(const int* __restrict__ entries,
                                              const int* __restrict__ bend,
                                              float* __restrict__ dis,
                                              int2* __restrict__ nodese, int N) {
  __shared__ int bin[64], sc[64];
  const int b = blockIdx.x;
  if (threadIdx.x < 64) bin[threadIdx.x] = 0;
  __syncthreads();
  int s0 = b * CAPB;
  int e1 = min(bend[b], s0 + CAPB);
  for (int i = s0 + threadIdx.x; i < e1; i += 256)
    atomicAdd(&bin[entries[i] & 63], 1);
  __syncthreads();

  // exclusive scan over 64 bins (proven R2 sortbuc preamble)
  int v = (threadIdx.x < 64) ? bin[threadIdx.x] : 0;
  if (threadIdx.x < 64) sc[threadIdx.x] = v;
  __syncthreads();
  for (int o = 1; o < 64; o <<= 1) {
    int t = (threadIdx.x < 64 && threadIdx.x >= (unsigned)o) ? sc[threadIdx.x - o] : 0;
    __syncthreads();
    if (threadIdx.x < 64) sc[threadIdx.x] += t;
    __syncthreads();
  }
  if (threadIdx.x < 64) {
    int gn = b * 64 + threadIdx.x;
    if (gn < N) {
      nodese[gn] = make_int2(sc[threadIdx.x] - v, v);   // bucket-local start, count
      dis[gn] = rsqrtf((float)(v + 1));                 // +1 self loop
    }
  }
}

// ---- aggsort v3: cursors from nodese; single entries pass; proven gather body ----
__global__ __launch_bounds__(512) void k_aggsort(const int* __restrict__ entries,
                                                 const int* __restrict__ bend,
                                                 const int2* __restrict__ nodese,
                                                 const uint* __restrict__ g32,
                                                 const float* __restrict__ dis,
                                                 float* __restrict__ out, int N) {
  __shared__ int slds[CAPB];
  __shared__ int cur[64], nst[64], ncn[64];
  const int b = blockIdx.x;
  const int s0 = b * CAPB;
  int tot = min(bend[b] - s0, CAPB);
  const int e0 = s0 + tot;

  if (threadIdx.x < 64) {
    int gn = b * 64 + threadIdx.x;
    int2 nv = (gn < N) ? nodese[gn] : make_int2(0, 0);
    nst[threadIdx.x] = nv.x;
    ncn[threadIdx.x] = nv.y;
    cur[threadIdx.x] = nv.x;
  }
  __syncthreads();

  // scatter sorted-by-dest srcs into LDS (the ONLY entries read here; NT last-use)
  for (int i = s0 + threadIdx.x; i < e0; i += 512) {
    int en = __builtin_nontemporal_load(entries + i);
    int p = atomicAdd(&cur[en & 63], 1);
    slds[p] = en >> 6;
  }
  __syncthreads();

  // gather: 8 waves x 8 nodes each, proven ILP-8 body
  const int wid = threadIdx.x >> 6, lane = threadIdx.x & 63;
  for (int j = 0; j < 8; ++j) {
    int ln = wid * 8 + j;
    int gn = b * 64 + ln;
    if (gn >= N) break;                // only trips in the final partial bucket
    int st = nst[ln], cn = ncn[ln];
    float dv = dis[gn];
    uint us = g32[(size_t)gn * 64 + lane];
    float ax = __uint_as_float(us << 16) * dv;          // self: dis_v * g_v
    float ay = __uint_as_float(us & 0xffff0000u) * dv;

    for (int base = 0; base < cn; base += 64) {
      int cnt = cn - base; if (cnt > 64) cnt = 64;
      int idx = base + lane;
      int my = (idx < cn) ? slds[st + idx] : 0;
      float dl = (idx < cn) ? dis[my] : 0.f;
      int k = 0;
      for (; k + 7 < cnt; k += 8) {
        int u0 = __shfl(my, k);     int u1 = __shfl(my, k + 1);
        int u2 = __shfl(my, k + 2); int u3 = __shfl(my, k + 3);
        int u4 = __shfl(my, k + 4); int u5 = __shfl(my, k + 5);
        int u6 = __shfl(my, k + 6); int u7 = __shfl(my, k + 7);
        float d0 = __shfl(dl, k);     float d1 = __shfl(dl, k + 1);
        float d2 = __shfl(dl, k + 2); float d3 = __shfl(dl, k + 3);
        float d4 = __shfl(dl, k + 4); float d5 = __shfl(dl, k + 5);
        float d6 = __shfl(dl, k + 6); float d7 = __shfl(dl, k + 7);
        uint a0 = g32[(size_t)u0 * 64 + lane];
        uint a1 = g32[(size_t)u1 * 64 + lane];
        uint a2 = g32[(size_t)u2 * 64 + lane];
        uint a3 = g32[(size_t)u3 * 64 + lane];
        uint a4 = g32[(size_t)u4 * 64 + lane];
        uint a5 = g32[(size_t)u5 * 64 + lane];
        uint a6 = g32[(size_t)u6 * 64 + lane];
        uint a7 = g32[(size_t)u7 * 64 + lane];
        ax = fmaf(d0, __uint_as_float(a0 << 16), ax);
        ay = fmaf(d0, __uint_as_float(a0 & 0xffff0000u), ay);
        ax = fmaf(d1, __uint_as_float(a1 << 16), ax);
        ay = fmaf(d1, __uint_as_float(a1 & 0xffff0000u), ay);
        ax = fmaf(d2, __uint_as_float(a2 << 16), ax);
        ay = fmaf(d2, __uint_as_float(a2 & 0xffff0000u), ay);
        ax = fmaf(d3, __uint_as_float(a3 << 16), ax);
        ay = fmaf(d3, __uint_as_float(a3 & 0xffff0000u), ay);
        ax = fmaf(d4, __uint_as_float(a4 << 16), ax);
        ay = fmaf(d4, __uint_as_float(a4 & 0xffff0000u), ay);
        ax = fmaf(d5, __uint_as_float(a5 << 16), ax);
        ay = fmaf(d5, __uint_as_float(a5 & 0xffff0000u), ay);
        ax = fmaf(d6, __uint_as_float(a6 << 16), ax);
        ay = fmaf(d6, __uint_as_float(a6 & 0xffff0000u), ay);
        ax = fmaf(d7, __uint_as_float(a7 << 16), ax);
        ay = fmaf(d7, __uint_as_float(a7 & 0xffff0000u), ay);
      }
      for (; k < cnt; ++k) {
        int u = __shfl(my, k);
        float du = __shfl(dl, k);
        uint a = g32[(size_t)u * 64 + lane];
        ax = fmaf(du, __uint_as_float(a << 16), ax);
        ay = fmaf(du, __uint_as_float(a & 0xffff0000u), ay);
      }
    }
    f32x2 o;
    o.x = fmaxf(ax * dv, 0.f);
    o.y = fmaxf(ay * dv, 0.f);
    __builtin_nontemporal_store(o, (f32x2*)out + (size_t)gn * 64 + lane);
  }
}

extern "C" void kernel_launch(void* const* d_in, const int* in_sizes, int n_in,
                              void* d_out, int out_size, void* d_ws, size_t ws_size,
                              hipStream_t stream) {
  const float* x  = (const float*)d_in[0];
  const int*   ei = (const int*)d_in[1];
  const float* W  = (const float*)d_in[2];
  const float* b  = (const float*)d_in[3];
  float* out = (float*)d_out;

  const int N = in_sizes[0] / D;
  const int E = in_sizes[1] / 2;
  const int NBUC = (N + 63) / 64;            // 1563 for N=100k (<= MAXBUC)

  char* ws = (char*)d_ws;
  size_t off = 0;
  ushort* g    = (ushort*)(ws + off); off += (size_t)N * D * 2;          // 25.6 MB
  off = (off + 255) & ~(size_t)255;
  float* dis   = (float*)(ws + off);  off += (size_t)N * 4;
  off = (off + 255) & ~(size_t)255;
  int2* nodese = (int2*)(ws + off);   off += (size_t)N * 8;
  off = (off + 255) & ~(size_t)255;
  int* bend    = (int*)(ws + off);    off += (size_t)NBUC * 4;
  off = (off + 255) & ~(size_t)255;
  int* hist    = (int*)(ws + off);    off += (size_t)NBUC * NHB * 4;     // 800 KB
  off = (off + 255) & ~(size_t)255;
  int* entries = (int*)(ws + off);    off += (size_t)NBUC * CAPB * 4;    // 12.8 MB

  k_gh<<<NHB + NBUC, 256, 0, stream>>>(x, W, b, g, N, ei, hist, E, NBUC);
  k_scatter<<<NHB, STH, 0, stream>>>(ei, hist, bend, entries, E, NBUC);
  k_disn<<<NBUC, 256, 0, stream>>>(entries, bend, dis, nodese, N);
  k_aggsort<<<NBUC, 512, 0, stream>>>(entries, bend, nodese, (const uint*)g, dis, out, N);
}